// Round 1
// baseline (2187.530 us; speedup 1.0000x reference)
//
#include <hip/hip_runtime.h>
#include <math.h>

// Model_39676907887961: out = dropout(softmax(x1@x2^T / x3)) @ x1 + x2
// B=2 H=16 S=2048 D=128; dropout p=0.5, jax.random.key(42), threefry2x32.
// Round 1: correctness-first vector-f32 flash kernel.
// PRNG hypothesis: jax_threefry_partitionable=True (JAX >= 0.4.36 default).
// Flip PARTITIONABLE to 0 if absmax comes back O(1).
#define PARTITIONABLE 1

constexpr int Bc = 2, Hc = 16, Sc = 2048, Dc = 128;
constexpr int BQ = 32, BK = 32;
constexpr int NT = Sc / BK;       // 64 k-tiles
constexpr int LDK = Dc + 4;      // padded LDS row stride (floats), 16B-aligned rows
constexpr int LDP = BK + 1;      // padded probs stride

__device__ __forceinline__ unsigned rotl32(unsigned x, int r) {
  return (x << r) | (x >> (32 - r));
}

// JAX Threefry-2x32, 20 rounds, key = (0, 42)  [jax.random.key(42)]
__device__ __forceinline__ void tf2x32(unsigned x0, unsigned x1,
                                       unsigned &o0, unsigned &o1) {
  const unsigned ks0 = 0u;
  const unsigned ks1 = 42u;
  const unsigned ks2 = 0x1BD11BDAu ^ 0u ^ 42u;
  x0 += ks0; x1 += ks1;
#define TFR(r) { x0 += x1; x1 = rotl32(x1, r); x1 ^= x0; }
  TFR(13) TFR(15) TFR(26) TFR(6)
  x0 += ks1; x1 += ks2 + 1u;
  TFR(17) TFR(29) TFR(16) TFR(24)
  x0 += ks2; x1 += ks0 + 2u;
  TFR(13) TFR(15) TFR(26) TFR(6)
  x0 += ks0; x1 += ks1 + 3u;
  TFR(17) TFR(29) TFR(16) TFR(24)
  x0 += ks1; x1 += ks2 + 4u;
  TFR(13) TFR(15) TFR(26) TFR(6)
  x0 += ks2; x1 += ks0 + 5u;
#undef TFR
  o0 = x0; o1 = x1;
}

// keep-probability 0.5: uniform(bits) < 0.5  <=>  MSB(bits) == 0
__device__ __forceinline__ float keepf(unsigned idx) {
#if PARTITIONABLE
  // partitionable path: x = (hi32(count)=0, lo32(count)=idx); bits = o0 ^ o1
  unsigned o0, o1;
  tf2x32(0u, idx, o0, o1);
  return ((o0 ^ o1) & 0x80000000u) ? 0.0f : 1.0f;
#else
  // original path: counts split in halves; i<HALF -> o0 of (i, i+HALF),
  // else o1 of (i-HALF, i). Same call either way, select the word.
  const unsigned HALF = 1u << 26;  // N/2, N = 2*16*2048*2048 = 2^27
  unsigned lo = (idx < HALF) ? idx : (idx - HALF);
  unsigned o0, o1;
  tf2x32(lo, lo + HALF, o0, o1);
  unsigned w = (idx < HALF) ? o0 : o1;
  return (w & 0x80000000u) ? 0.0f : 1.0f;
#endif
}

__global__ __launch_bounds__(256)
void attn_fwd(const float* __restrict__ x1, const float* __restrict__ x2,
              const float* __restrict__ x3, float* __restrict__ out) {
  __shared__ float Qs[BQ * LDK];
  __shared__ float Ks[BK * LDK];
  __shared__ float Vs[BK * LDK];
  __shared__ float Ps[BQ * LDP];

  const int tid = threadIdx.x;
  const int qt = blockIdx.x;        // 0..63 q-tile
  const int bh = blockIdx.y;        // 0..31 (b*H + h)
  const int q_local = tid >> 3;     // 0..31 row within tile
  const int g = tid & 7;            // 0..7  8 lanes cooperate per row
  const int q_glob = qt * BQ + q_local;

  const float inv_div = 1.0f / x3[bh];

  const float* X1 = x1 + (size_t)bh * Sc * Dc;   // Q and V source
  const float* X2 = x2 + (size_t)bh * Sc * Dc;   // K and residual source

  // ---- stage Q tile: 32x128 floats, contiguous, coalesced float4 ----
  {
    const float4* src = (const float4*)(X1 + (size_t)qt * BQ * Dc);
#pragma unroll
    for (int i = 0; i < 4; ++i) {
      int f = tid + 256 * i;        // 0..1023 float4 index
      int row = f >> 5;             // 32 float4 per row
      int c = f & 31;
      *((float4*)&Qs[row * LDK + c * 4]) = src[f];
    }
  }

  float acc[16];
#pragma unroll
  for (int i = 0; i < 16; ++i) acc[i] = 0.0f;
  float m_run = -INFINITY;
  float l_run = 0.0f;

  const unsigned row_base = ((unsigned)(bh * Sc + q_glob)) * (unsigned)Sc;

  for (int t = 0; t < NT; ++t) {
    __syncthreads();  // prev-iter readers of Ks/Vs/Ps done
    // ---- stage K (x2) and V (x1) tiles ----
    {
      const float4* ksrc = (const float4*)(X2 + (size_t)t * BK * Dc);
      const float4* vsrc = (const float4*)(X1 + (size_t)t * BK * Dc);
#pragma unroll
      for (int i = 0; i < 4; ++i) {
        int f = tid + 256 * i;
        int row = f >> 5;
        int c = f & 31;
        *((float4*)&Ks[row * LDK + c * 4]) = ksrc[f];
        *((float4*)&Vs[row * LDK + c * 4]) = vsrc[f];
      }
    }
    __syncthreads();

    // ---- scores: this thread owns k = g, g+8, g+16, g+24 of row q_local ----
    float s0 = 0.f, s1 = 0.f, s2 = 0.f, s3 = 0.f;
    {
      const float* qrow = &Qs[q_local * LDK];
      const float* kr0 = &Ks[(g + 0) * LDK];
      const float* kr1 = &Ks[(g + 8) * LDK];
      const float* kr2 = &Ks[(g + 16) * LDK];
      const float* kr3 = &Ks[(g + 24) * LDK];
#pragma unroll 8
      for (int d = 0; d < Dc; ++d) {
        float qv = qrow[d];
        s0 = fmaf(qv, kr0[d], s0);
        s1 = fmaf(qv, kr1[d], s1);
        s2 = fmaf(qv, kr2[d], s2);
        s3 = fmaf(qv, kr3[d], s3);
      }
    }
    s0 *= inv_div; s1 *= inv_div; s2 *= inv_div; s3 *= inv_div;

    // ---- online softmax row stats (8-lane butterfly, same result all lanes) --
    float lm = fmaxf(fmaxf(s0, s1), fmaxf(s2, s3));
    lm = fmaxf(lm, __shfl_xor(lm, 1));
    lm = fmaxf(lm, __shfl_xor(lm, 2));
    lm = fmaxf(lm, __shfl_xor(lm, 4));
    float m_new = fmaxf(m_run, lm);
    float alpha = __expf(m_run - m_new);   // first iter: exp(-inf) = 0
    float p0 = __expf(s0 - m_new);
    float p1 = __expf(s1 - m_new);
    float p2 = __expf(s2 - m_new);
    float p3 = __expf(s3 - m_new);
    float ls = p0 + p1 + p2 + p3;
    ls += __shfl_xor(ls, 1);
    ls += __shfl_xor(ls, 2);
    ls += __shfl_xor(ls, 4);
    l_run = l_run * alpha + ls;   // denominator: dropout does NOT affect it
    m_run = m_new;

    // ---- dropout mask (deterministic threefry) + stage masked numerators ----
    {
      unsigned base = row_base + (unsigned)(t * BK);
      Ps[q_local * LDP + g + 0]  = p0 * keepf(base + g + 0);
      Ps[q_local * LDP + g + 8]  = p1 * keepf(base + g + 8);
      Ps[q_local * LDP + g + 16] = p2 * keepf(base + g + 16);
      Ps[q_local * LDP + g + 24] = p3 * keepf(base + g + 24);
    }
    __syncthreads();

    // ---- PV accumulate: this thread owns row q_local, cols g*16..g*16+15 ----
#pragma unroll
    for (int c = 0; c < 16; ++c) acc[c] *= alpha;
    {
      const float* prow = &Ps[q_local * LDP];
#pragma unroll 4
      for (int k = 0; k < BK; ++k) {
        float pk = prow[k];
        const float4* vr = (const float4*)&Vs[k * LDK + g * 16];
        float4 v0 = vr[0], v1 = vr[1], v2 = vr[2], v3 = vr[3];
        acc[0]  = fmaf(pk, v0.x, acc[0]);
        acc[1]  = fmaf(pk, v0.y, acc[1]);
        acc[2]  = fmaf(pk, v0.z, acc[2]);
        acc[3]  = fmaf(pk, v0.w, acc[3]);
        acc[4]  = fmaf(pk, v1.x, acc[4]);
        acc[5]  = fmaf(pk, v1.y, acc[5]);
        acc[6]  = fmaf(pk, v1.z, acc[6]);
        acc[7]  = fmaf(pk, v1.w, acc[7]);
        acc[8]  = fmaf(pk, v2.x, acc[8]);
        acc[9]  = fmaf(pk, v2.y, acc[9]);
        acc[10] = fmaf(pk, v2.z, acc[10]);
        acc[11] = fmaf(pk, v2.w, acc[11]);
        acc[12] = fmaf(pk, v3.x, acc[12]);
        acc[13] = fmaf(pk, v3.y, acc[13]);
        acc[14] = fmaf(pk, v3.z, acc[14]);
        acc[15] = fmaf(pk, v3.w, acc[15]);
      }
    }
  }

  // ---- epilogue: out = (1/(1-p)) * acc / l + x2 residual ----
  const float invl = 2.0f / l_run;
  float* orow = out + ((size_t)bh * Sc + q_glob) * Dc + g * 16;
  const float* x2row = X2 + (size_t)q_glob * Dc + g * 16;
#pragma unroll
  for (int c = 0; c < 16; c += 4) {
    float4 xv = *((const float4*)&x2row[c]);
    float4 ov;
    ov.x = fmaf(acc[c + 0], invl, xv.x);
    ov.y = fmaf(acc[c + 1], invl, xv.y);
    ov.z = fmaf(acc[c + 2], invl, xv.z);
    ov.w = fmaf(acc[c + 3], invl, xv.w);
    *((float4*)&orow[c]) = ov;
  }
}

extern "C" void kernel_launch(void* const* d_in, const int* in_sizes, int n_in,
                              void* d_out, int out_size, void* d_ws, size_t ws_size,
                              hipStream_t stream) {
  const float* x1 = (const float*)d_in[0];
  const float* x2 = (const float*)d_in[1];
  const float* x3 = (const float*)d_in[2];
  float* out = (float*)d_out;
  dim3 grid(Sc / BQ, Bc * Hc);   // 64 q-tiles x 32 (b,h)
  attn_fwd<<<grid, 256, 0, stream>>>(x1, x2, x3, out);
}

// Round 2
// 443.008 us; speedup vs baseline: 4.9379x; 4.9379x over previous
//
#include <hip/hip_runtime.h>
#include <math.h>

// Model_39676907887961: out = dropout(softmax(x1@x2^T / x3)) @ x1 + x2
// B=2 H=16 S=2048 D=128. Round 2: MFMA flash kernel (32x32x16 bf16).
// S^T = K·Q^T (C-layout col = q-row -> per-lane softmax state);
// O^T = V^T·P^T (V staged transposed+swizzled, P via LDS round-trip).
// Dropout: JAX threefry2x32 key(42), partitionable path (verified round 1),
// applied as bit-mask on packed bf16 P in LDS.

constexpr int Sc = 2048, Dc = 128;
constexpr int BQ = 128, BK = 64, NTILES = Sc / BK;
constexpr int LDK = 132;   // ushorts per Ks row (264B: 2-way banks, b64-aligned)
constexpr int LDP = 68;    // ushorts per Ps row
constexpr int LDOE = 68;   // floats per Os row (epilogue, b128-aligned)

typedef short bf16x8 __attribute__((ext_vector_type(8)));
typedef float f32x16 __attribute__((ext_vector_type(16)));
union U8 { uint4 u; bf16x8 v; };

__device__ __forceinline__ unsigned rotl32(unsigned x, int r) {
  return (x << r) | (x >> (32 - r));
}

// JAX Threefry-2x32, 20 rounds, key = (0, 42)
__device__ __forceinline__ void tf2x32(unsigned x0, unsigned x1,
                                       unsigned &o0, unsigned &o1) {
  const unsigned ks0 = 0u, ks1 = 42u;
  const unsigned ks2 = 0x1BD11BDAu ^ 0u ^ 42u;
  x0 += ks0; x1 += ks1;
#define TFR(r) { x0 += x1; x1 = rotl32(x1, r); x1 ^= x0; }
  TFR(13) TFR(15) TFR(26) TFR(6)
  x0 += ks1; x1 += ks2 + 1u;
  TFR(17) TFR(29) TFR(16) TFR(24)
  x0 += ks2; x1 += ks0 + 2u;
  TFR(13) TFR(15) TFR(26) TFR(6)
  x0 += ks0; x1 += ks1 + 3u;
  TFR(17) TFR(29) TFR(16) TFR(24)
  x0 += ks1; x1 += ks2 + 4u;
  TFR(13) TFR(15) TFR(26) TFR(6)
  x0 += ks2; x1 += ks0 + 5u;
#undef TFR
  o0 = x0; o1 = x1;
}

__device__ __forceinline__ unsigned keepbit(unsigned idx) {
  unsigned o0, o1; tf2x32(0u, idx, o0, o1);
  return (((o0 ^ o1) >> 31) ^ 1u);   // 1 = keep (uniform < 0.5 <=> MSB==0)
}

// pack two f32 -> two bf16 (RNE), lo = a, hi = b
__device__ __forceinline__ unsigned pk2(float a, float b) {
  unsigned ua = __float_as_uint(a), ub = __float_as_uint(b);
  ua += 0x7fffu + ((ua >> 16) & 1u);
  ub += 0x7fffu + ((ub >> 16) & 1u);
  return (ua >> 16) | (ub & 0xffff0000u);
}

__global__ __launch_bounds__(256, 2)
void attn_mfma(const float* __restrict__ x1, const float* __restrict__ x2,
               const float* __restrict__ x3, float* __restrict__ out) {
  __shared__ alignas(16) char smem[64*LDK*2 + 128*64*2 + 4*32*LDP*2];
  ushort* Ks = (ushort*)smem;                           // [64][LDK]
  ushort* Vt = (ushort*)(smem + 64*LDK*2);              // [128][64] swizzled
  ushort* Ps = (ushort*)(smem + 64*LDK*2 + 128*64*2);   // [4][32][LDP]
  float*  Os = (float*)smem;                            // epilogue overlay [128][LDOE]

  const int tid = threadIdx.x;
  const int wave = tid >> 6, lane = tid & 63;
  const int r = lane & 31, h = lane >> 5;
  const int blk = blockIdx.x;
  const int bh = blk & 31, qt = blk >> 5;   // same-bh blocks 32 apart -> same XCD slot

  const float* X1 = x1 + (size_t)bh * Sc * Dc;   // Q and V source
  const float* X2 = x2 + (size_t)bh * Sc * Dc;   // K and residual source
  float* outp = out + (size_t)bh * Sc * Dc;
  const float inv_div = 1.0f / x3[bh];

  const int qrow = qt * BQ + wave * 32 + r;      // this lane's softmax row
  const unsigned row_base = (unsigned)(bh * Sc + qrow) * (unsigned)Sc;

  // ---- Q fragments (B-operand of S^T mfma), registers for whole kernel ----
  bf16x8 qf[8];
  {
    const float4* qsrc = (const float4*)(X1 + (size_t)qrow * Dc);
#pragma unroll
    for (int ch = 0; ch < 8; ++ch) {
      float4 f0 = qsrc[ch*4 + h*2 + 0];
      float4 f1 = qsrc[ch*4 + h*2 + 1];
      U8 cv; cv.u = uint4{pk2(f0.x,f0.y), pk2(f0.z,f0.w), pk2(f1.x,f1.y), pk2(f1.z,f1.w)};
      qf[ch] = cv.v;
    }
  }

  f32x16 o0 = {}, o1 = {}, o2 = {}, o3 = {};   // O^T acc: d-tiles 0..3
  float m_run = -INFINITY, l_run = 0.0f;

  for (int t = 0; t < NTILES; ++t) {
    __syncthreads();
    // ---- stage K (x2) -> Ks, f32->bf16, coalesced ----
    {
      const float4* ksrc = (const float4*)(X2 + (size_t)t * BK * Dc);
#pragma unroll
      for (int it = 0; it < 8; ++it) {
        int f = tid + 256*it;
        int key = f >> 5, c = f & 31;
        float4 kv = ksrc[f];
        uint2 w; w.x = pk2(kv.x, kv.y); w.y = pk2(kv.z, kv.w);
        *(uint2*)&Ks[key*LDK + c*4] = w;
      }
    }
    // ---- stage V (x1) -> Vt transposed [d][key], swizzled kb'=(kb+(d>>2)+4(d&3))&15
    {
      const float* vbase = X1 + (size_t)t * BK * Dc;
#pragma unroll
      for (int it = 0; it < 2; ++it) {
        int g = tid + 256*it;
        int c = g & 31, kb = g >> 5;   // d-quad, key-quad
        const float4* vs = (const float4*)(vbase + (size_t)(kb*4) * Dc) + c;
        float4 a0 = vs[0], a1 = vs[32], a2 = vs[64], a3 = vs[96];
        float e0[4] = {a0.x,a0.y,a0.z,a0.w};
        float e1[4] = {a1.x,a1.y,a1.z,a1.w};
        float e2[4] = {a2.x,a2.y,a2.z,a2.w};
        float e3[4] = {a3.x,a3.y,a3.z,a3.w};
#pragma unroll
        for (int i = 0; i < 4; ++i) {
          int d = c*4 + i;
          int pkb = (kb + c + 4*i) & 15;
          uint2 w; w.x = pk2(e0[i], e1[i]); w.y = pk2(e2[i], e3[i]);
          *(uint2*)&Vt[d*64 + pkb*4] = w;
        }
      }
    }
    __syncthreads();

    // ---- S^T = K·Q^T : A = K rows (m=key), B = Q regs (n=q-row) ----
    f32x16 s0v = {}, s1v = {};
    {
      const ushort* ka0 = &Ks[(     r)*LDK + h*8];
      const ushort* ka1 = &Ks[(32 + r)*LDK + h*8];
#pragma unroll
      for (int ch = 0; ch < 8; ++ch) {
        uint2 u00 = *(const uint2*)&ka0[ch*16];
        uint2 u01 = *(const uint2*)&ka0[ch*16 + 4];
        uint2 u10 = *(const uint2*)&ka1[ch*16];
        uint2 u11 = *(const uint2*)&ka1[ch*16 + 4];
        U8 c0; c0.u = uint4{u00.x,u00.y,u01.x,u01.y};
        U8 c1; c1.u = uint4{u10.x,u10.y,u11.x,u11.y};
        s0v = __builtin_amdgcn_mfma_f32_32x32x16_bf16(c0.v, qf[ch], s0v, 0,0,0);
        s1v = __builtin_amdgcn_mfma_f32_32x32x16_bf16(c1.v, qf[ch], s1v, 0,0,0);
      }
    }

    // ---- online softmax (row = lane&31; only cross-lane partner is lane^32) ----
    float sv0[16], sv1[16];
    float mx = -INFINITY;
#pragma unroll
    for (int i = 0; i < 16; ++i) {
      sv0[i] = s0v[i] * inv_div; sv1[i] = s1v[i] * inv_div;
      mx = fmaxf(mx, fmaxf(sv0[i], sv1[i]));
    }
    mx = fmaxf(mx, __shfl_xor(mx, 32));
    float m_new = fmaxf(m_run, mx);
    float alpha = __expf(m_run - m_new);
    float ls = 0.0f;
#pragma unroll
    for (int i = 0; i < 16; ++i) {
      sv0[i] = __expf(sv0[i] - m_new); ls += sv0[i];
      sv1[i] = __expf(sv1[i] - m_new); ls += sv1[i];
    }
    ls += __shfl_xor(ls, 32);
    l_run = l_run * alpha + ls;   // denominator excludes dropout
    m_run = m_new;

    // ---- pack P (pre-dropout) -> Ps[wave][row][key], b64 writes ----
    ushort* pw = Ps + wave*(32*LDP) + r*LDP;
#pragma unroll
    for (int mt = 0; mt < 2; ++mt)
#pragma unroll
      for (int rg = 0; rg < 4; ++rg) {
        int k0 = mt*32 + rg*8 + h*4;
        const float* sp = mt ? sv1 : sv0;   // folds after unroll
        uint2 w; w.x = pk2(sp[rg*4+0], sp[rg*4+1]); w.y = pk2(sp[rg*4+2], sp[rg*4+3]);
        *(uint2*)&pw[k0] = w;
      }

    // ---- dropout: threefry bit-mask on packed bf16 (rolled: small I-cache) ----
    {
      unsigned idx0 = row_base + (unsigned)(t * BK) + (unsigned)(h * 4);
#pragma unroll 1
      for (int g = 0; g < 8; ++g) {
        int kk = (g >> 2)*32 + (g & 3)*8;
        int k0 = kk + h*4;
        unsigned ib = idx0 + (unsigned)kk;
        uint2 w = *(uint2*)&pw[k0];
        unsigned m0 = (keepbit(ib+0) ? 0x0000ffffu : 0u) | (keepbit(ib+1) ? 0xffff0000u : 0u);
        unsigned m1 = (keepbit(ib+2) ? 0x0000ffffu : 0u) | (keepbit(ib+3) ? 0xffff0000u : 0u);
        w.x &= m0; w.y &= m1;
        *(uint2*)&pw[k0] = w;
      }
    }

    // ---- O^T = alpha*O^T + V^T·P^T ----
#pragma unroll
    for (int i = 0; i < 16; ++i) { o0[i]*=alpha; o1[i]*=alpha; o2[i]*=alpha; o3[i]*=alpha; }
#pragma unroll
    for (int ch = 0; ch < 4; ++ch) {
      uint2 b0 = *(const uint2*)&pw[ch*16 + h*8];
      uint2 b1 = *(const uint2*)&pw[ch*16 + h*8 + 4];
      U8 bf; bf.u = uint4{b0.x,b0.y,b1.x,b1.y};
      int kb0 = ch*4 + h*2;
#pragma unroll
      for (int dmt = 0; dmt < 4; ++dmt) {
        int d = dmt*32 + r;
        int sw = (d >> 2) + 4*(d & 3);
        int p0 = (kb0     + sw) & 15;
        int p1 = (kb0 + 1 + sw) & 15;
        uint2 aa = *(const uint2*)&Vt[d*64 + p0*4];
        uint2 bb = *(const uint2*)&Vt[d*64 + p1*4];
        U8 af; af.u = uint4{aa.x,aa.y,bb.x,bb.y};
        f32x16& oc = dmt==0 ? o0 : dmt==1 ? o1 : dmt==2 ? o2 : o3;
        oc = __builtin_amdgcn_mfma_f32_32x32x16_bf16(af.v, bf.v, oc, 0,0,0);
      }
    }
  }

  // ---- epilogue: O^T -> LDS transpose (2 halves) -> +x2 residual -> out ----
  const float invl = 2.0f / l_run;   // 1/(1-p) * 1/l
#pragma unroll
  for (int half = 0; half < 2; ++half) {
    __syncthreads();
    {
      float* ow = Os + (size_t)(wave*32 + r) * LDOE;
#pragma unroll
      for (int dm = 0; dm < 2; ++dm) {
        const int dmt = half*2 + dm;
        const f32x16& oc = dmt==0 ? o0 : dmt==1 ? o1 : dmt==2 ? o2 : o3;
#pragma unroll
        for (int rg = 0; rg < 4; ++rg) {
          int dd = dm*32 + rg*8 + h*4;
          float2 w0{oc[rg*4+0]*invl, oc[rg*4+1]*invl};
          float2 w1{oc[rg*4+2]*invl, oc[rg*4+3]*invl};
          *(float2*)&ow[dd]     = w0;
          *(float2*)&ow[dd + 2] = w1;
        }
      }
    }
    __syncthreads();
#pragma unroll
    for (int it = 0; it < 8; ++it) {
      int f = tid + 256*it;
      int q = f >> 4, cc = f & 15;
      const float4 ov = *(const float4*)&Os[q*LDOE + cc*4];
      size_t goff = (size_t)(qt*BQ + q) * Dc + half*64 + cc*4;
      const float4 xv = *(const float4*)&X2[goff];
      float4 res{ov.x+xv.x, ov.y+xv.y, ov.z+xv.z, ov.w+xv.w};
      *(float4*)&outp[goff] = res;
    }
  }
}

extern "C" void kernel_launch(void* const* d_in, const int* in_sizes, int n_in,
                              void* d_out, int out_size, void* d_ws, size_t ws_size,
                              hipStream_t stream) {
  const float* x1 = (const float*)d_in[0];
  const float* x2 = (const float*)d_in[1];
  const float* x3 = (const float*)d_in[2];
  float* out = (float*)d_out;
  dim3 grid(32 * (Sc / BQ));   // 512 blocks: bh = blk&31, qt = blk>>5
  attn_mfma<<<grid, 256, 0, stream>>>(x1, x2, x3, out);
}